// Round 4
// baseline (167.349 us; speedup 1.0000x reference)
//
#include <hip/hip_runtime.h>

typedef _Float16 half8 __attribute__((ext_vector_type(8)));
typedef float floatx4 __attribute__((ext_vector_type(4)));

#define NF 40
#define NE 128
#define NP 780        // NF*(NF-1)/2
#define NPT 784       // padded to 49*16
#define NMT 49        // m-tiles of 16 pairs
#define XHB 5120      // f16 elems per batch elem (40*128)
#define NB 1024       // batch (fixed by problem: in_sizes[0]=5242880)

// workspace layout (bytes); total ~13.1 MB
#define OFF_XH 0              // _Float16 x_h[1024*5120]      = 10485760 B
#define OFF_WH 10485760       // _Float16 w_h[128*128]        =    32768 B
#define OFF_IJ 10518528       // ushort  ij[784]               =     1568 B (+pad)
#define OFF_SC 10520576       // float   sc[1024*784]          =  3211264 B

// K0 flat work ranges (8 elems per item for conversions)
#define NX8 655360            // x chunks
#define NW8 2048              // W chunks
#define T_IJ 657408
#define T_END 658192

__device__ __forceinline__ half8 cvt8(const float* s) {
    float4 v0 = *(const float4*)s;
    float4 v1 = *(const float4*)(s + 4);
    half8 h;
    h[0] = (_Float16)v0.x; h[1] = (_Float16)v0.y;
    h[2] = (_Float16)v0.z; h[3] = (_Float16)v0.w;
    h[4] = (_Float16)v1.x; h[5] = (_Float16)v1.y;
    h[6] = (_Float16)v1.z; h[7] = (_Float16)v1.w;
    return h;
}

__global__ __launch_bounds__(256, 4)
void k0_prep(const float* __restrict__ xg, const float* __restrict__ wg,
             _Float16* __restrict__ xh, _Float16* __restrict__ wh,
             unsigned short* __restrict__ ij)
{
    int T = blockIdx.x * 256 + threadIdx.x;
    if (T < NX8) {
        *(half8*)(xh + (size_t)T * 8) = cvt8(xg + (size_t)T * 8);
    } else if (T < NX8 + NW8) {
        int t = T - NX8;
        *(half8*)(wh + t * 8) = cvt8(wg + t * 8);
    } else if (T < T_END) {
        int p = T - T_IJ;
        unsigned short v = 0;
        if (p < NP) {
            int i = 0, rem = p;
            while (rem >= (NF - 1 - i)) { rem -= (NF - 1 - i); ++i; }
            v = (unsigned short)((i << 8) | (i + 1 + rem));
        }
        ij[p] = v;
    }
}

// One wave = one 16-pair m-tile x 8 batch elems. W frags register-resident,
// A frags straight from L2-hot x_h. No LDS, no barriers.
__global__ __launch_bounds__(256, 2)
void k1_scores(const _Float16* __restrict__ xh, const _Float16* __restrict__ wh,
               const unsigned short* __restrict__ ij,
               const float* __restrict__ wbg, const float* __restrict__ hg,
               float* __restrict__ sc)
{
    const int wid  = threadIdx.x >> 6;
    const int lane = threadIdx.x & 63;
    const unsigned wave = blockIdx.x * 4 + wid;     // 0..6271
    const int mt    = wave % NMT;                   // m-tile
    const int chunk = wave / NMT;                   // b-chunk 0..127
    const int col  = lane & 15;
    const int quad = lane >> 4;
    const int p0   = mt * 16;

    // B-fragments: B[n=col][k=quad*8+j] = W[a=n*16+col][e=k*32+quad*8+j]
    half8 bfrag[8][4];
#pragma unroll
    for (int n = 0; n < 8; ++n)
#pragma unroll
        for (int k = 0; k < 4; ++k)
            bfrag[n][k] = *(const half8*)(wh + (n * 16 + col) * NE + k * 32 + quad * 8);

    float wbr[8], hr[8];
#pragma unroll
    for (int n = 0; n < 8; ++n) {
        wbr[n] = wbg[n * 16 + col];
        hr[n]  = hg[n * 16 + col];
    }

    const int v    = ij[p0 + col];                  // fixed pair per lane, all 8 b's
    const int ro_i = ((v >> 8) & 255) * NE;
    const int ro_j = (v & 255) * NE;

    for (int bi = 0; bi < 8; ++bi) {
        const int b = chunk * 8 + bi;
        const _Float16* xb = xh + (size_t)b * XHB;

        floatx4 acc[8];
#pragma unroll
        for (int n = 0; n < 8; ++n) acc[n] = (floatx4){0.f, 0.f, 0.f, 0.f};

#pragma unroll
        for (int k = 0; k < 4; ++k) {
            const int koff = k * 32 + quad * 8;
            half8 ai = *(const half8*)(xb + ro_i + koff);
            half8 aj = *(const half8*)(xb + ro_j + koff);
            half8 af = ai * aj;                     // v_pk_mul_f16 x4
#pragma unroll
            for (int n = 0; n < 8; ++n)
                acc[n] = __builtin_amdgcn_mfma_f32_16x16x32_f16(af, bfrag[n][k], acc[n], 0, 0, 0);
        }

        // scores[p] = sum_a relu(S[p,a]+wb[a])*h[a]  (h_b cancels in softmax)
        float ps[4] = {0.f, 0.f, 0.f, 0.f};
#pragma unroll
        for (int n = 0; n < 8; ++n)
#pragma unroll
            for (int r = 0; r < 4; ++r)
                ps[r] += fmaxf(acc[n][r] + wbr[n], 0.f) * hr[n];
#pragma unroll
        for (int r = 0; r < 4; ++r)
#pragma unroll
            for (int off = 1; off < 16; off <<= 1)
                ps[r] += __shfl_xor(ps[r], off);
        if (col == 0) {
            float* scb = sc + (size_t)b * NPT + p0 + quad * 4;
#pragma unroll
            for (int r = 0; r < 4; ++r)
                if (p0 + quad * 4 + r < NP) scb[r] = ps[r];
        }
    }
}

// Per-b tail: softmax over 780 pairs, afm, final dot. (R3-verified logic.)
__global__ __launch_bounds__(256, 4)
void k2_out(const _Float16* __restrict__ xh, const float* __restrict__ scg,
            const unsigned short* __restrict__ ijg,
            const float* __restrict__ pwg, const float* __restrict__ pbg,
            float* __restrict__ out)
{
    __shared__ _Float16 xs[NF][136];        // 10880 B, stride 272 B
    __shared__ float sc[NPT];               // 3136 B
    __shared__ unsigned short ij[NPT];      // 1568 B
    __shared__ float afmp[16][NE];          // 8192 B
    __shared__ float redm[4], reds[4], redo[2];

    const int tid  = threadIdx.x;
    const int b    = blockIdx.x;
    const int lane = tid & 63;
    const int wid  = tid >> 6;

    const _Float16* xb = xh + (size_t)b * XHB;
    for (int t = tid; t < NF * 16; t += 256) {
        int row = t >> 4, kb = t & 15;
        *(half8*)&xs[row][kb * 8] = *(const half8*)(xb + row * NE + kb * 8);
    }
    const float* scb = scg + (size_t)b * NPT;
    for (int p = tid; p < NPT; p += 256) {
        if (p < NP) sc[p] = scb[p];
        ij[p] = ijg[p];
    }
    __syncthreads();

    // softmax (unnormalized exp; fold 1/sum into final scalar)
    float m = -1e30f;
    for (int p = tid; p < NP; p += 256) m = fmaxf(m, sc[p]);
#pragma unroll
    for (int off = 1; off < 64; off <<= 1) m = fmaxf(m, __shfl_xor(m, off));
    if (lane == 0) redm[wid] = m;
    __syncthreads();
    const float M = fmaxf(fmaxf(redm[0], redm[1]), fmaxf(redm[2], redm[3]));

    float s = 0.f;
    for (int p = tid; p < NP; p += 256) {
        float e = __expf(sc[p] - M);
        sc[p] = e;
        s += e;
    }
#pragma unroll
    for (int off = 1; off < 64; off <<= 1) s += __shfl_xor(s, off);
    if (lane == 0) reds[wid] = s;
    __syncthreads();

    // afm[e] = sum_p exp_p * xi[e]*xj[e]  (fp32 accum over f16 products)
    const int q  = tid >> 4;          // 16 pair-chunks of <=49
    const int kb = tid & 15;          // 8-element e-block
    float a[8];
#pragma unroll
    for (int r = 0; r < 8; ++r) a[r] = 0.f;
    const int pbeg = q * 49;
    const int pend = (pbeg + 49 < NP) ? (pbeg + 49) : NP;
    for (int p = pbeg; p < pend; ++p) {
        int vv = ij[p];
        float w = sc[p];
        half8 hi = *(const half8*)&xs[(vv >> 8) & 255][kb * 8];
        half8 hj = *(const half8*)&xs[vv & 255][kb * 8];
        half8 pr = hi * hj;
#pragma unroll
        for (int r = 0; r < 8; ++r) a[r] += w * (float)pr[r];
    }
#pragma unroll
    for (int r = 0; r < 8; ++r) afmp[q][kb * 8 + r] = a[r];
    __syncthreads();

    // out[b] = dot(afm_un, pw) / sum_exp + p_b
    float vv2 = 0.f;
    if (tid < NE) {
        float acc2 = 0.f;
#pragma unroll
        for (int qq = 0; qq < 16; ++qq) acc2 += afmp[qq][tid];
        vv2 = acc2 * pwg[tid];
    }
#pragma unroll
    for (int off = 1; off < 64; off <<= 1) vv2 += __shfl_xor(vv2, off);
    if (tid < NE && lane == 0) redo[wid] = vv2;
    __syncthreads();
    if (tid == 0) {
        float S   = reds[0] + reds[1] + reds[2] + reds[3];
        float tot = redo[0] + redo[1];
        out[b] = tot / S + pbg[0];
    }
}

extern "C" void kernel_launch(void* const* d_in, const int* in_sizes, int n_in,
                              void* d_out, int out_size, void* d_ws, size_t ws_size,
                              hipStream_t stream) {
    const float* xg  = (const float*)d_in[0];  // x [1024,40,128]
    const float* wg  = (const float*)d_in[1];  // attn_w_w [128,128]
    const float* wbg = (const float*)d_in[2];  // attn_w_b [128]
    const float* hg  = (const float*)d_in[3];  // attn_h_w [1,128]
    // d_in[4] = attn_h_b : cancels in softmax
    const float* pwg = (const float*)d_in[5];  // attn_p_w [1,128]
    const float* pbg = (const float*)d_in[6];  // attn_p_b [1]

    char* ws = (char*)d_ws;
    _Float16* xh = (_Float16*)(ws + OFF_XH);
    _Float16* wh = (_Float16*)(ws + OFF_WH);
    unsigned short* ij = (unsigned short*)(ws + OFF_IJ);
    float* sc = (float*)(ws + OFF_SC);

    k0_prep<<<(T_END + 255) / 256, 256, 0, stream>>>(xg, wg, xh, wh, ij);
    k1_scores<<<NB * NMT / 32, 256, 0, stream>>>(xh, wh, ij, wbg, hg, sc); // 6272 waves / 4
    k2_out<<<NB, 256, 0, stream>>>(xh, sc, ij, pwg, pbg, (float*)d_out);
}